// Round 6
// baseline (293.309 us; speedup 1.0000x reference)
//
#include <hip/hip_runtime.h>
#include <hip/hip_bf16.h>
#include <math.h>

// ChordAwareTransformer bf16-MFMA pipeline, round 12.
//   Qcat=[pitch_q|harmony_q|voice_q] (d=192) vs Kcat=[k|chord_f|bass_f]
// R12: attn rebuilt around per-CU LDS-read throughput model (fits R8/R10/R11:
// dur ~= #ds_read_b128 per CU x 12cyc when >=2 barrier domains):
//  * 32x32x16 MFMA (2x FLOP per 16B fragment read vs 16x16x32)
//  * 2 q-tiles per wave (64 q): each K-frag read feeds 2 MFMAs
//  * P fully in-register: cvt_pk pairs + v_permlane32_swap_b32 build PV
//    A-frags from QK^T C/D regs (partner lanes share q). Zero P LDS traffic.
//  * 2 waves/block, ATQ=128, KVBLK=64, 32 kts, LDS 64KB -> 2 blocks/CU,
//    512 blocks = exactly 2/CU. launch_bounds(128,1): VGPR cap 512, no
//    spill trap (R9 lesson); ~240 VGPR, 1 wave/SIMD by design.
// Per-CU b128 reads: 4 waves x 32/kt x 32 kt = 4.1K (R8: 17.4K) -> ~21us floor.
// MFMA 32x32 layouts: A[m=lane&31][k=(lane>>5)*8+j], B[k=(lane>>5)*8+j]
// [n=lane&31], C/D col=lane&31, row=(reg&3)+8*(reg>>2)+4*(lane>>5) (m74/m101).

#define D_    1024
#define H_    16
#define B_    2
#define S_    2048
#define M_    (B_*S_)
#define NCAT_ 5120

#define QSCALE_ (1.44269504f / 24.0f)   // log2e * (1/sqrt(64)) / 3

#if __has_builtin(__builtin_amdgcn_exp2f)
#define EXP2(x) __builtin_amdgcn_exp2f(x)
#else
#define EXP2(x) exp2f(x)
#endif

typedef __attribute__((ext_vector_type(8))) short s16x8;
typedef __attribute__((ext_vector_type(4))) float f32x4;
typedef __attribute__((ext_vector_type(16))) float f32x16;

__device__ __forceinline__ unsigned short f2bf(float f) {
    unsigned u = __builtin_bit_cast(unsigned, f);
    u += 0x7fff + ((u >> 16) & 1);          // RNE
    return (unsigned short)(u >> 16);
}
// packed f32x2 -> bf16x2 (v_cvt_pk_bf16_f32, RNE); low short = a
__device__ __forceinline__ unsigned pk2(float a, float b) {
    __hip_bfloat162 h = __float22bfloat162_rn(float2{a, b});
    unsigned r;
    __builtin_memcpy(&r, &h, 4);
    return r;
}

#define GLDS16(gp, lp) \
    __builtin_amdgcn_global_load_lds((const __attribute__((address_space(1))) void*)(gp), \
                                     (__attribute__((address_space(3))) void*)(lp), 16, 0, 0)

// ---------------------------------------------------------------- prep (fused)
struct PrepArgs {
    const float* x;
    const float* pitch_pc; const float* bass_pc;
    const float* Wc; const float* bc;
    const float* Wb; const float* bb;
    const float* wsrc[6]; unsigned short* wdst[6];
    const float* bsrc[5]; float* bias5;
    unsigned short* xb; unsigned short* cfb; unsigned short* bfb;
};

__global__ __launch_bounds__(256) void prep_kernel(PrepArgs a) {
    __shared__ unsigned short t[64][72];
    int bx = blockIdx.x;
    const int tid = threadIdx.x;

    if (bx < 4096) {                       // ---- cvt_x (fp32 -> bf16)
        int i = (bx * 256 + tid) * 4;
        float4 v = *(const float4*)(a.x + i);
        uint2 o = {pk2(v.x, v.y), pk2(v.z, v.w)};
        *(uint2*)(a.xb + i) = o;
        return;
    }
    bx -= 4096;
    if (bx < 1536) {                       // ---- wtrans (6 weights, 64x64 tiles)
        int z = bx >> 8, rem = bx & 255;
        const float* src = a.wsrc[z];
        unsigned short* dst = a.wdst[z];
        int k0 = (rem >> 4) * 64, n0 = (rem & 15) * 64;
        int r = tid >> 2, c0 = (tid & 3) * 16;
#pragma unroll
        for (int i = 0; i < 4; ++i) {
            float4 v = *(const float4*)(src + (size_t)(k0 + r) * 1024 + n0 + c0 + i * 4);
            ushort4 o = {f2bf(v.x), f2bf(v.y), f2bf(v.z), f2bf(v.w)};
            *(ushort4*)&t[r][c0 + i * 4] = o;
        }
        __syncthreads();
#pragma unroll
        for (int i = 0; i < 4; ++i) {
            ushort4 o = {t[c0 + i*4 + 0][r], t[c0 + i*4 + 1][r],
                         t[c0 + i*4 + 2][r], t[c0 + i*4 + 3][r]};
            *(ushort4*)(dst + (size_t)(n0 + r) * 1024 + k0 + c0 + i * 4) = o;
        }
        return;
    }
    bx -= 1536;
    if (bx < 20) {                         // ---- bpack
        int i = bx * 256 + tid;
        a.bias5[i] = a.bsrc[i >> 10][i & 1023];
        return;
    }
    bx -= 20;
    {                                      // ---- feat x2
        const float* pc;  const float* W;  const float* bias;  unsigned short* out;
        if (bx < 8192) { pc = a.pitch_pc; W = a.Wc; bias = a.bc; out = a.cfb; }
        else { bx -= 8192; pc = a.bass_pc; W = a.Wb; bias = a.bb; out = a.bfb; }
        int idx = bx * 256 + tid;
        int s = idx >> 10, c = idx & 1023;
        float acc = bias[c];
#pragma unroll
        for (int i = 0; i < 12; ++i)
            acc = fmaf(pc[s * 12 + i], W[i * 1024 + c], acc);
        out[idx] = f2bf(acc);
    }
}

// ---------------------------------------------------------------- MFMA GEMM
// C[M x N] = A[M x 1024] @ Bt^T + bias.  BK=32, double-buffered, one barrier
// per K-tile. Per buffer: A 128x32 bf16 (8 KB) @0, B @8192. Row = 4 chunks of
// 16 B; chunk at pos p holds source chunk p ^ ((row>>1)&3).
// MODE 0: N=5120; wsel 0..2 scaled by QSCALE_, wsel 3 plain, wsel 4 -> Vt^T.
// MODE 1: N=1024, fp32 out.
template<int MODE>
__global__ __launch_bounds__(256) void gemm_k(
    const unsigned short* __restrict__ A, const unsigned short* __restrict__ Bt,
    const float* __restrict__ bias, unsigned short* __restrict__ Cb,
    unsigned short* __restrict__ Vt, float* __restrict__ Cf)
{
    __shared__ __align__(16) unsigned char lds[32768];   // buf0@0, buf1@16384
    const int tid = threadIdx.x;
    const int wv = tid >> 6, lane = tid & 63;
    const int lq = lane & 15, quad = lane >> 4;
    const int wm = wv >> 1, wn = wv & 1;
    const int m0 = blockIdx.y * 128, n0 = blockIdx.x * 128;

    const int sr = lane >> 2;
    const int sc = (lane & 3) ^ ((lane >> 3) & 3);
    const unsigned short* Abase = A + (size_t)m0 * 1024 + sc * 8;
    const unsigned short* Bbase = Bt + (size_t)n0 * 1024 + sc * 8;

    f32x4 acc[4][4] = {};

    // prologue: stage tile 0 -> buf0
#pragma unroll
    for (int j = 0; j < 2; ++j) {
        int seg = wv * 2 + j;
        GLDS16(Abase + (size_t)(seg * 16 + sr) * 1024, lds + seg * 1024);
        GLDS16(Bbase + (size_t)(seg * 16 + sr) * 1024, lds + 8192 + seg * 1024);
    }

    for (int kt = 0; kt < 32; ++kt) {
        __syncthreads();   // stage(kt) drained; all waves done compute(kt-1)
        unsigned char* cur = lds + (kt & 1) * 16384;

        if (kt + 1 < 32) {   // stage(kt+1) -> other buf (overlaps compute)
            const int k0n = (kt + 1) * 32;
            unsigned char* dst = lds + ((kt + 1) & 1) * 16384;
#pragma unroll
            for (int j = 0; j < 2; ++j) {
                int seg = wv * 2 + j;
                GLDS16(Abase + (size_t)(seg * 16 + sr) * 1024 + k0n, dst + seg * 1024);
                GLDS16(Bbase + (size_t)(seg * 16 + sr) * 1024 + k0n, dst + 8192 + seg * 1024);
            }
        }

        s16x8 aF[4], bF[4];
#pragma unroll
        for (int mi = 0; mi < 4; ++mi) {
            int row = wm * 64 + mi * 16 + lq;
            aF[mi] = *(const s16x8*)(cur + row * 64 + ((quad ^ ((row >> 1) & 3)) * 16));
        }
#pragma unroll
        for (int ni = 0; ni < 4; ++ni) {
            int row = wn * 64 + ni * 16 + lq;
            bF[ni] = *(const s16x8*)(cur + 8192 + row * 64 + ((quad ^ ((row >> 1) & 3)) * 16));
        }
#pragma unroll
        for (int mi = 0; mi < 4; ++mi)
#pragma unroll
            for (int ni = 0; ni < 4; ++ni)
                acc[mi][ni] = __builtin_amdgcn_mfma_f32_16x16x32_bf16(
                    aF[mi], bF[ni], acc[mi][ni], 0, 0, 0);
    }

    if (MODE == 0) {
        const int wsel = n0 >> 10;
        const float sc2 = (wsel <= 2) ? QSCALE_ : 1.0f;
#pragma unroll
        for (int ni = 0; ni < 4; ++ni) {
            int n = n0 + wn * 64 + ni * 16 + lq;
            float bv = bias[n];
            if (wsel == 4) {
                int nl = n - 4096, h = nl >> 6, d = nl & 63;
#pragma unroll
                for (int mi = 0; mi < 4; ++mi) {
                    int mrow = m0 + wm * 64 + mi * 16 + quad * 4;
                    uint2 w = {pk2(acc[mi][ni][0] + bv, acc[mi][ni][1] + bv),
                               pk2(acc[mi][ni][2] + bv, acc[mi][ni][3] + bv)};
                    *(uint2*)(Vt + ((size_t)h * 64 + d) * (size_t)M_ + mrow) = w;
                }
            } else {
#pragma unroll
                for (int mi = 0; mi < 4; ++mi) {
                    int mrow = m0 + wm * 64 + mi * 16 + quad * 4;
#pragma unroll
                    for (int r = 0; r < 4; ++r)
                        Cb[(size_t)(mrow + r) * NCAT_ + n] = f2bf((acc[mi][ni][r] + bv) * sc2);
                }
            }
        }
    } else {
#pragma unroll
        for (int ni = 0; ni < 4; ++ni) {
            int n = n0 + wn * 64 + ni * 16 + lq;
            float bv = bias[n];
#pragma unroll
            for (int mi = 0; mi < 4; ++mi) {
                int mrow = m0 + wm * 64 + mi * 16 + quad * 4;
#pragma unroll
                for (int r = 0; r < 4; ++r)
                    Cf[(size_t)(mrow + r) * 1024 + n] = acc[mi][ni][r] + bv;
            }
        }
    }
}

// ---------------------------------------------------------------- attention
// Block: one (b,h), 128 queries, 128 thr (2 waves x 64 q = 2 q-tiles of 32).
// 32 K-tiles of 64 keys. MFMA 32x32x16.
// LDS 65536: buf0@0, buf1@32768. Per buf (4 segs x [64 rows][128B], chunk c
// of row r stored at pos c^(r&7)): K seg0 @0 (k), seg1 @8192 (chord),
// seg2 @16384 (bass), V @24576 ([64 d][64 keys x 2B]).
// Staging per kt: wave0 segs 0,1; wave1 seg2 + V; 16 GLDS16/wave.
// QK^T: A=K[m=key32][k=d16], B=Q[k=d16][n=q32] (Q in regs, 12 frags/qtile).
// C/D: col=lane&31(=q), rows=keys (reg&3)+8*(reg>>2)+4*hi.
// P in-reg: exp2 -> cvt_pk pairs -> 2x v_permlane32_swap_b32 per 16-key
// slice gives PV A-frag [m=q][k=key] (partner lanes share q).
// PV: B=V[k=key16][n=d32] from LDS. O C/D: col=d, rows=q.
// 512 blocks = 2/CU (128KB LDS): 2 barrier domains. launch_bounds(128,1):
// VGPR cap 512 (no spill; ~240 used, 1 wave/SIMD by design).
#define ATQ_ 128
#define KVB_ 64

__global__ __launch_bounds__(128, 1) void attn_kernel(
    const unsigned short* __restrict__ Q5b, const unsigned short* __restrict__ cfb,
    const unsigned short* __restrict__ bfb, const unsigned short* __restrict__ Vtg,
    unsigned short* __restrict__ ctxb)
{
    extern __shared__ __align__(16) unsigned char smem[];
    const int tid = threadIdx.x;
    const int wv = tid >> 6, lane = tid & 63;   // wv 0..1
    const int ln31 = lane & 31, hi = lane >> 5;
    const int bh = blockIdx.x;
    const int b = bh >> 4, h = bh & 15;
    const int q0 = blockIdx.y * ATQ_;
    const int lr = lane >> 3;                   // staging row-in-part (0..7)
    const int g = (lane & 7) ^ lr;              // staging source chunk

    // ---- staging sources: wave0 = {K keys, chord}, wave1 = {bass, V}
    const unsigned short *spA, *spB;
    unsigned incA, incB, pstA, pstB;
    if (wv == 0) {
        spA = Q5b + (size_t)(b * S_ + lr) * NCAT_ + 3072 + h * 64 + g * 8;
        incA = 64 * NCAT_;  pstA = 8 * NCAT_;
        spB = cfb + (size_t)lr * 1024 + h * 64 + g * 8;
        incB = 64 * 1024;   pstB = 8 * 1024;
    } else {
        spA = bfb + (size_t)lr * 1024 + h * 64 + g * 8;
        incA = 64 * 1024;   pstA = 8 * 1024;
        spB = Vtg + (size_t)(h * 64 + lr) * (size_t)M_ + b * S_ + g * 8;
        incB = 64;          pstB = 8 * M_;
    }
    incA = __builtin_amdgcn_readfirstlane(incA);
    incB = __builtin_amdgcn_readfirstlane(incB);
    pstA = __builtin_amdgcn_readfirstlane(pstA);
    pstB = __builtin_amdgcn_readfirstlane(pstB);
    const unsigned lofs = wv * 16384;

    // ---- Q -> regs: qf[qtile][dk]: B-frag [k=d16][n=q32]
    s16x8 qf[2][12];
#pragma unroll
    for (int qt = 0; qt < 2; ++qt) {
        const unsigned short* qp = Q5b
            + (size_t)(b * S_ + q0 + wv * 64 + qt * 32 + ln31) * NCAT_
            + h * 64 + hi * 8;
#pragma unroll
        for (int dk = 0; dk < 12; ++dk)
            qf[qt][dk] = *(const s16x8*)(qp + (dk >> 2) * 1024 + (dk & 3) * 16);
    }

    f32x16 o[2][2] = {};    // [qtile][dtile]
    float lp[2] = {0.f, 0.f};

    // ---- prologue: stage tile 0 -> buf0
#pragma unroll
    for (int j = 0; j < 8; ++j) {
        GLDS16(spA + (size_t)j * pstA, smem + lofs + j * 1024);
        GLDS16(spB + (size_t)j * pstB, smem + lofs + 8192 + j * 1024);
    }
    spA += incA; spB += incB;

    for (int kt = 0; kt < 32; ++kt) {
        __syncthreads();   // stage(kt) drained; all waves past compute(kt-1)
        unsigned char* cur = smem + (kt & 1) * 32768;

        if (kt + 1 < 32) {   // stage(kt+1) -> other buf (overlaps compute)
            unsigned char* dst = smem + ((kt + 1) & 1) * 32768;
#pragma unroll
            for (int j = 0; j < 8; ++j) {
                GLDS16(spA + (size_t)j * pstA, dst + lofs + j * 1024);
                GLDS16(spB + (size_t)j * pstB, dst + lofs + 8192 + j * 1024);
            }
            spA += incA; spB += incB;
        }

#pragma unroll
        for (int kb = 0; kb < 2; ++kb) {
            // ---- QK^T: st[qt] over 32 keys (kb half) x 32 q, d=192
            f32x16 st0 = {}, st1 = {};
            const int keyl = kb * 32 + ln31;
            const int krow = keyl * 128;
            const int ksw = keyl & 7;
            __builtin_amdgcn_s_setprio(1);
#pragma unroll
            for (int dk = 0; dk < 12; ++dk) {
                s16x8 kf = *(const s16x8*)(cur + (dk >> 2) * 8192 + krow
                                           + ((((dk & 3) * 2 + hi) ^ ksw) * 16));
                st0 = __builtin_amdgcn_mfma_f32_32x32x16_bf16(kf, qf[0][dk], st0, 0, 0, 0);
                st1 = __builtin_amdgcn_mfma_f32_32x32x16_bf16(kf, qf[1][dk], st1, 0, 0, 0);
            }
            __builtin_amdgcn_s_setprio(0);

            // ---- softmax (fixed-max, pre-scaled by QSCALE_ in gemm0) +
            //      in-register P A-frags via cvt_pk + permlane32_swap
            s16x8 pa[2][2];   // [qtile][sub-slice]
#pragma unroll
            for (int qt = 0; qt < 2; ++qt) {
                f32x16 st = qt ? st1 : st0;
                float p[16];
#pragma unroll
                for (int r = 0; r < 16; ++r) p[r] = EXP2(st[r]);
                lp[qt] += ((p[0] + p[1]) + (p[2] + p[3]))
                        + ((p[4] + p[5]) + (p[6] + p[7]))
                        + ((p[8] + p[9]) + (p[10] + p[11]))
                        + ((p[12] + p[13]) + (p[14] + p[15]));
#pragma unroll
                for (int ss = 0; ss < 2; ++ss) {
                    unsigned w0 = pk2(p[ss * 8 + 0], p[ss * 8 + 1]);
                    unsigned w1 = pk2(p[ss * 8 + 2], p[ss * 8 + 3]);
                    unsigned w2 = pk2(p[ss * 8 + 4], p[ss * 8 + 5]);
                    unsigned w3 = pk2(p[ss * 8 + 6], p[ss * 8 + 7]);
                    // dst-hi <-> src-lo swap: frag gets partner-lane halves
                    asm volatile("v_permlane32_swap_b32 %0, %1"
                                 : "+v"(w0), "+v"(w2));
                    asm volatile("v_permlane32_swap_b32 %0, %1"
                                 : "+v"(w1), "+v"(w3));
                    unsigned u4[4] = {w0, w1, w2, w3};
                    __builtin_memcpy(&pa[qt][ss], u4, 16);
                }
            }

            // ---- PV for this kb: O += P @ V, slices s = kb*2+ss (16 keys)
            __builtin_amdgcn_s_setprio(1);
#pragma unroll
            for (int dt = 0; dt < 2; ++dt) {
                const int drow = dt * 32 + ln31;
                const int dsw = drow & 7;
#pragma unroll
                for (int ss = 0; ss < 2; ++ss) {
                    const int s = kb * 2 + ss;
                    s16x8 vf = *(const s16x8*)(cur + 24576 + drow * 128
                                               + (((s * 2 + hi) ^ dsw) * 16));
                    o[0][dt] = __builtin_amdgcn_mfma_f32_32x32x16_bf16(pa[0][ss], vf, o[0][dt], 0, 0, 0);
                    o[1][dt] = __builtin_amdgcn_mfma_f32_32x32x16_bf16(pa[1][ss], vf, o[1][dt], 0, 0, 0);
                }
            }
            __builtin_amdgcn_s_setprio(0);
        }
    }

    // ---- epilogue: l lives at lane q=ln31 (both halves after xor-32).
    // O rows are q = (r&3)+8*(r>>2)+4*hi; cols d = dt*32+ln31.
#pragma unroll
    for (int qt = 0; qt < 2; ++qt) {
        lp[qt] += __shfl_xor(lp[qt], 32);
        float inv = 1.0f / lp[qt];
#pragma unroll
        for (int r = 0; r < 16; ++r) {
            int qrow = (r & 3) + 8 * (r >> 2) + 4 * hi;
            float iv = __shfl(inv, qrow);
            int row = q0 + wv * 64 + qt * 32 + qrow;
#pragma unroll
            for (int dt = 0; dt < 2; ++dt)
                ctxb[(size_t)(b * S_ + row) * 1024 + h * 64 + dt * 32 + ln31] =
                    f2bf(o[qt][dt][r] * iv);
        }
    }
}

// ---------------------------------------------------------------- launch
extern "C" void kernel_launch(void* const* d_in, const int* in_sizes, int n_in,
                              void* d_out, int out_size, void* d_ws, size_t ws_size,
                              hipStream_t stream)
{
    const float* x        = (const float*)d_in[0];
    const float* pitch_pc = (const float*)d_in[1];
    const float* bass_pc  = (const float*)d_in[2];
    const float* Wpq = (const float*)d_in[3];   const float* bpq = (const float*)d_in[4];
    const float* Whq = (const float*)d_in[5];   const float* bhq = (const float*)d_in[6];
    const float* Wvq = (const float*)d_in[7];   const float* bvq = (const float*)d_in[8];
    const float* Wk  = (const float*)d_in[9];   const float* bk  = (const float*)d_in[10];
    const float* Wv  = (const float*)d_in[11];  const float* bv  = (const float*)d_in[12];
    const float* Wo  = (const float*)d_in[13];  const float* bo  = (const float*)d_in[14];
    const float* Wc  = (const float*)d_in[15];  const float* bc  = (const float*)d_in[16];
    const float* Wb  = (const float*)d_in[17];  const float* bb  = (const float*)d_in[18];

    char* ws = (char*)d_ws;
    unsigned short* xb   = (unsigned short*)(ws);                      // 8 MB
    unsigned short* W5t  = (unsigned short*)(ws + 8388608);            // 10 MB
    unsigned short* Wot  = (unsigned short*)(ws + 18874368);           // 2 MB
    float*          bias5= (float*)         (ws + 20971520);           // 20 KB
    unsigned short* cfb  = (unsigned short*)(ws + 20992000);           // 4 MB
    unsigned short* bfb  = (unsigned short*)(ws + 25186304);           // 4 MB
    unsigned short* Q5b  = (unsigned short*)(ws + 29380608);           // 40 MB
    unsigned short* Vtg  = (unsigned short*)(ws + 71323648);           // 8 MB
    unsigned short* ctxb = (unsigned short*)(ws + 79712256);           // 8 MB

    PrepArgs pa;
    pa.x = x; pa.pitch_pc = pitch_pc; pa.bass_pc = bass_pc;
    pa.Wc = Wc; pa.bc = bc; pa.Wb = Wb; pa.bb = bb;
    pa.wsrc[0] = Wpq; pa.wsrc[1] = Whq; pa.wsrc[2] = Wvq;
    pa.wsrc[3] = Wk;  pa.wsrc[4] = Wv;  pa.wsrc[5] = Wo;
    for (int i = 0; i < 5; ++i) pa.wdst[i] = W5t + (size_t)i * 1024 * 1024;
    pa.wdst[5] = Wot;
    pa.bsrc[0] = bpq; pa.bsrc[1] = bhq; pa.bsrc[2] = bvq; pa.bsrc[3] = bk; pa.bsrc[4] = bv;
    pa.bias5 = bias5; pa.xb = xb; pa.cfb = cfb; pa.bfb = bfb;

    prep_kernel<<<dim3(4096 + 1536 + 20 + 8192 + 8192), 256, 0, stream>>>(pa);

    gemm_k<0><<<dim3(40, 32), 256, 0, stream>>>(xb, W5t, bias5, Q5b, Vtg, nullptr);

    attn_kernel<<<dim3(B_ * H_, S_ / ATQ_), 128, 65536, stream>>>(Q5b, cfb, bfb, Vtg, ctxb);

    gemm_k<1><<<dim3(8, 32), 256, 0, stream>>>(ctxb, Wot, bo, nullptr, nullptr, (float*)d_out);
}

// Round 7
// 283.358 us; speedup vs baseline: 1.0351x; 1.0351x over previous
//
#include <hip/hip_runtime.h>
#include <hip/hip_bf16.h>
#include <math.h>

// ChordAwareTransformer bf16-MFMA pipeline, round 13.
// R13: RANK-12 SCORE REFACTOR. harmony_q.chord_f == (harmony_q@Wc_h^T).pitch_pc
// (+ a key-independent shift hq.bc that softmax cancels). Same for voice/bass.
// So QK inner dim: 192 -> 64(k)+12(pc)+12(bass)+8 pad = 96.
//   Q96[m, h*96+ 0..63] = pitch_q*QS   [64..75] = hq12*QS  [80..91] = vq12*QS
//   K96[m, h*96+ 0..63] = k            [64..75] = pitch_pc [80..91] = bass_pc
//   pads 76..79 / 92..95 zeroed on both sides.
// gemm0 N: 5120 -> 3456 (27 tiles). attn: R8 structure (best, 85us), QK MFMA
// 24->12 per wave-kt, K staging 24KB->12KB/tile, Q direct global->VGPR.
// Weight fold Whcvt[384,1024] = per-head Whq@Wc^T | Wvq@Wb^T in prep.
// MFMA layouts (HW-verified): A[m=lane&15][k=quad*8+j], B[k][n=lane&15],
// C/D row=quad*4+reg, col=lane&15.

#define D_    1024
#define H_    16
#define B_    2
#define S_    2048
#define M_    (B_*S_)
#define QROW_ 1536          // Q96/K96 row stride in shorts (16 heads * 96)

#define QSCALE_ (1.44269504f / 24.0f)   // log2e * (1/sqrt(64)) / 3

#if __has_builtin(__builtin_amdgcn_exp2f)
#define EXP2(x) __builtin_amdgcn_exp2f(x)
#else
#define EXP2(x) exp2f(x)
#endif

typedef __attribute__((ext_vector_type(8))) short s16x8;
typedef __attribute__((ext_vector_type(4))) float f32x4;

__device__ __forceinline__ unsigned short f2bf(float f) {
    unsigned u = __builtin_bit_cast(unsigned, f);
    u += 0x7fff + ((u >> 16) & 1);          // RNE
    return (unsigned short)(u >> 16);
}
__device__ __forceinline__ unsigned pk2(float a, float b) {
    __hip_bfloat162 h = __float22bfloat162_rn(float2{a, b});
    unsigned r;
    __builtin_memcpy(&r, &h, 4);
    return r;
}

#define GLDS16(gp, lp) \
    __builtin_amdgcn_global_load_lds((const __attribute__((address_space(1))) void*)(gp), \
                                     (__attribute__((address_space(3))) void*)(lp), 16, 0, 0)

// ---------------------------------------------------------------- prep (fused)
struct PrepArgs {
    const float* x;
    const float* pitch_pc; const float* bass_pc;
    const float* Wc; const float* Wb;
    const float* Whq; const float* bhq;
    const float* Wvq; const float* bvq;
    const float* wsrc[4]; unsigned short* wdst[4];   // Wpq,Wk,Wv,Wo
    const float* bsrc[3]; float* bias5;              // bpq,bk,bv
    unsigned short* Whcvt;                           // 384 x 1024 (Bt rows 3072..3455)
    unsigned short* xb; unsigned short* Q96; unsigned short* K96;
};

__global__ __launch_bounds__(256) void prep_kernel(PrepArgs a) {
    __shared__ unsigned short t[64][72];
    int bx = blockIdx.x;
    const int tid = threadIdx.x;

    if (bx < 4096) {                       // ---- cvt_x (fp32 -> bf16)
        int i = (bx * 256 + tid) * 4;
        float4 v = *(const float4*)(a.x + i);
        uint2 o = {pk2(v.x, v.y), pk2(v.z, v.w)};
        *(uint2*)(a.xb + i) = o;
        return;
    }
    bx -= 4096;
    if (bx < 1024) {                       // ---- wtrans (4 weights, 64x64 tiles)
        int z = bx >> 8, rem = bx & 255;
        const float* src = a.wsrc[z];
        unsigned short* dst = a.wdst[z];
        int k0 = (rem >> 4) * 64, n0 = (rem & 15) * 64;
        int r = tid >> 2, c0 = (tid & 3) * 16;
#pragma unroll
        for (int i = 0; i < 4; ++i) {
            float4 v = *(const float4*)(src + (size_t)(k0 + r) * 1024 + n0 + c0 + i * 4);
            ushort4 o = {f2bf(v.x), f2bf(v.y), f2bf(v.z), f2bf(v.w)};
            *(ushort4*)&t[r][c0 + i * 4] = o;
        }
        __syncthreads();
#pragma unroll
        for (int i = 0; i < 4; ++i) {
            ushort4 o = {t[c0 + i*4 + 0][r], t[c0 + i*4 + 1][r],
                         t[c0 + i*4 + 2][r], t[c0 + i*4 + 3][r]};
            *(ushort4*)(dst + (size_t)(n0 + r) * 1024 + k0 + c0 + i * 4) = o;
        }
        return;
    }
    bx -= 1024;
    if (bx < 12) {                         // ---- bpack (bpq,bk,bv)
        int i = bx * 256 + tid;
        a.bias5[i] = a.bsrc[i >> 10][i & 1023];
        return;
    }
    bx -= 12;
    if (bx < 384) {                        // ---- fold: Whcvt row j (Bt layout)
        int j = bx;
        int h = j / 24, r = j - h * 24;
        const float* src = (r < 12) ? a.Whq : a.Wvq;
        const float* pcw = (r < 12) ? a.Wc  : a.Wb;
        const float* bsr = (r < 12) ? a.bhq : a.bvq;
        int i = (r < 12) ? r : r - 12;
        int hb = h * 64;
#pragma unroll
        for (int ro = 0; ro < 4; ++ro) {
            int row = tid + ro * 256;
            float acc = 0.f;
#pragma unroll
            for (int d = 0; d < 64; ++d)
                acc = fmaf(src[(size_t)row * 1024 + hb + d], pcw[i * 1024 + hb + d], acc);
            a.Whcvt[(size_t)j * 1024 + row] = f2bf(acc);
        }
        if (tid == 0) {
            float bacc = 0.f;
            for (int d = 0; d < 64; ++d)
                bacc = fmaf(bsr[hb + d], pcw[i * 1024 + hb + d], bacc);
            a.bias5[3072 + j] = bacc;
        }
        return;
    }
    bx -= 384;
    {                                      // ---- pcpack: K96 pc cols + pads; Q96 pads
        int idx = bx * 256 + tid;          // 65536 = M*H
        int m = idx >> 4, h = idx & 15;
        int s = m & (S_ - 1);
        unsigned short buf[32];
#pragma unroll
        for (int i = 0; i < 12; ++i) buf[i] = f2bf(a.pitch_pc[s * 12 + i]);
        buf[12] = buf[13] = buf[14] = buf[15] = 0;
#pragma unroll
        for (int i = 0; i < 12; ++i) buf[16 + i] = f2bf(a.bass_pc[s * 12 + i]);
        buf[28] = buf[29] = buf[30] = buf[31] = 0;
        unsigned short* kd = a.K96 + (size_t)m * QROW_ + h * 96 + 64;
#pragma unroll
        for (int i = 0; i < 4; ++i)
            *(uint4*)(kd + i * 8) = *(uint4*)&buf[i * 8];
        unsigned short* qd = a.Q96 + (size_t)m * QROW_ + h * 96 + 64;
        uint2 z = {0u, 0u};
        *(uint2*)(qd + 12) = z;            // cols 76..79
        *(uint2*)(qd + 28) = z;            // cols 92..95
    }
}

// ---------------------------------------------------------------- MFMA GEMM
// C[M x N] = A[M x 1024] @ Bt^T + bias.  BK=32, double-buffered, one barrier
// per K-tile. Per buffer: A 128x32 bf16 @0, B @8192; chunk p holds source
// chunk p ^ ((row>>1)&3).
// MODE 0 (N=3456): wsel0 pitch_q*QS -> Q96 col h*96+d; wsel1 k -> K96;
//   wsel2 v -> Vt^T; wsel3 (384 cols) hq/vq*QS -> Q96 cols 64+r / 68+r.
// MODE 1: N=1024, fp32 out.
template<int MODE>
__global__ __launch_bounds__(256) void gemm_k(
    const unsigned short* __restrict__ A, const unsigned short* __restrict__ Bt,
    const float* __restrict__ bias, unsigned short* __restrict__ Qb,
    unsigned short* __restrict__ Kb, unsigned short* __restrict__ Vt,
    float* __restrict__ Cf)
{
    __shared__ __align__(16) unsigned char lds[32768];
    const int tid = threadIdx.x;
    const int wv = tid >> 6, lane = tid & 63;
    const int lq = lane & 15, quad = lane >> 4;
    const int wm = wv >> 1, wn = wv & 1;
    const int m0 = blockIdx.y * 128, n0 = blockIdx.x * 128;

    const int sr = lane >> 2;
    const int sc = (lane & 3) ^ ((lane >> 3) & 3);
    const unsigned short* Abase = A + (size_t)m0 * 1024 + sc * 8;
    const unsigned short* Bbase = Bt + (size_t)n0 * 1024 + sc * 8;

    f32x4 acc[4][4] = {};

#pragma unroll
    for (int j = 0; j < 2; ++j) {
        int seg = wv * 2 + j;
        GLDS16(Abase + (size_t)(seg * 16 + sr) * 1024, lds + seg * 1024);
        GLDS16(Bbase + (size_t)(seg * 16 + sr) * 1024, lds + 8192 + seg * 1024);
    }

    for (int kt = 0; kt < 32; ++kt) {
        __syncthreads();
        unsigned char* cur = lds + (kt & 1) * 16384;

        if (kt + 1 < 32) {
            const int k0n = (kt + 1) * 32;
            unsigned char* dst = lds + ((kt + 1) & 1) * 16384;
#pragma unroll
            for (int j = 0; j < 2; ++j) {
                int seg = wv * 2 + j;
                GLDS16(Abase + (size_t)(seg * 16 + sr) * 1024 + k0n, dst + seg * 1024);
                GLDS16(Bbase + (size_t)(seg * 16 + sr) * 1024 + k0n, dst + 8192 + seg * 1024);
            }
        }

        s16x8 aF[4], bF[4];
#pragma unroll
        for (int mi = 0; mi < 4; ++mi) {
            int row = wm * 64 + mi * 16 + lq;
            aF[mi] = *(const s16x8*)(cur + row * 64 + ((quad ^ ((row >> 1) & 3)) * 16));
        }
#pragma unroll
        for (int ni = 0; ni < 4; ++ni) {
            int row = wn * 64 + ni * 16 + lq;
            bF[ni] = *(const s16x8*)(cur + 8192 + row * 64 + ((quad ^ ((row >> 1) & 3)) * 16));
        }
#pragma unroll
        for (int mi = 0; mi < 4; ++mi)
#pragma unroll
            for (int ni = 0; ni < 4; ++ni)
                acc[mi][ni] = __builtin_amdgcn_mfma_f32_16x16x32_bf16(
                    aF[mi], bF[ni], acc[mi][ni], 0, 0, 0);
    }

    if (MODE == 0) {
        const int wsel = n0 >> 10;
#pragma unroll
        for (int ni = 0; ni < 4; ++ni) {
            int n = n0 + wn * 64 + ni * 16 + lq;
            float bv = bias[n];
            if (wsel == 2) {               // v -> Vt^T (bf16 pairs)
                int nl = n - 2048, h = nl >> 6, d = nl & 63;
#pragma unroll
                for (int mi = 0; mi < 4; ++mi) {
                    int mrow = m0 + wm * 64 + mi * 16 + quad * 4;
                    uint2 w = {pk2(acc[mi][ni][0] + bv, acc[mi][ni][1] + bv),
                               pk2(acc[mi][ni][2] + bv, acc[mi][ni][3] + bv)};
                    *(uint2*)(Vt + ((size_t)h * 64 + d) * (size_t)M_ + mrow) = w;
                }
            } else if (wsel == 3) {        // hq/vq -> Q96, scaled
                int j = n - 3072;
                int h = j / 24, r = j - h * 24;
                int col = h * 96 + (r < 12 ? 64 + r : 68 + r);
#pragma unroll
                for (int mi = 0; mi < 4; ++mi) {
                    int mrow = m0 + wm * 64 + mi * 16 + quad * 4;
#pragma unroll
                    for (int rr = 0; rr < 4; ++rr)
                        Qb[(size_t)(mrow + rr) * QROW_ + col] =
                            f2bf((acc[mi][ni][rr] + bv) * QSCALE_);
                }
            } else {                       // wsel0: pitch_q*QS -> Q96; wsel1: k -> K96
                int nl = n & 1023;
                int col = (nl >> 6) * 96 + (nl & 63);
                unsigned short* dstp = (wsel == 0) ? Qb : Kb;
                float sc2 = (wsel == 0) ? QSCALE_ : 1.0f;
#pragma unroll
                for (int mi = 0; mi < 4; ++mi) {
                    int mrow = m0 + wm * 64 + mi * 16 + quad * 4;
#pragma unroll
                    for (int rr = 0; rr < 4; ++rr)
                        dstp[(size_t)(mrow + rr) * QROW_ + col] =
                            f2bf((acc[mi][ni][rr] + bv) * sc2);
                }
            }
        }
    } else {
#pragma unroll
        for (int ni = 0; ni < 4; ++ni) {
            int n = n0 + wn * 64 + ni * 16 + lq;
            float bv = bias[n];
#pragma unroll
            for (int mi = 0; mi < 4; ++mi) {
                int mrow = m0 + wm * 64 + mi * 16 + quad * 4;
#pragma unroll
                for (int rr = 0; rr < 4; ++rr)
                    Cf[(size_t)(mrow + rr) * 1024 + n] = acc[mi][ni][rr] + bv;
            }
        }
    }
}

// ---------------------------------------------------------------- attention
// R8 structure, d=96. Block: one (b,h), 128 q, 512 thr (8 waves x 16 q).
// 32 K-tiles of 64 keys. LDS 57344: bufs @0/@20480 (20KB each: K seg0
// [64k][128B] @0 pos c^(key&7); K seg1 [64k][64B] @8192 pos c^((key>>1)&3);
// V [64d][128B] @12288 pos c^(d&7)); P @40960 [128q][128B] pos c^(q&7).
// Staging 20 slots/kt: t<8 seg0, 8..11 seg1, 12..19 V; wave w: slots
// {w, w+8, w+16(w<4)}. Q direct global->VGPR (3 frags).
#define ATQ_ 128

__global__ __launch_bounds__(512, 2) void attn_kernel(
    const unsigned short* __restrict__ Q96, const unsigned short* __restrict__ K96,
    const unsigned short* __restrict__ Vtg, unsigned short* __restrict__ ctxb)
{
    extern __shared__ __align__(16) unsigned char smem[];
    const int tid = threadIdx.x;
    const int wv = tid >> 6, lane = tid & 63;   // wv 0..7
    const int lq = lane & 15, quad = lane >> 4;
    const int bh = blockIdx.x;
    const int b = bh >> 4, h = bh & 15;
    const int q0 = blockIdx.y * ATQ_;
    const int lr = lane >> 3;                   // 128B-row staging: row-in-KB
    const int g = (lane & 7) ^ lr;              // source chunk
    const int g4 = (lane & 3) ^ ((lane >> 3) & 3);  // 64B-row staging chunk

    // ---- staging slots: A=wv (K seg0), B=wv+8, C=wv+16 (wv<4 only)
    const unsigned short* sp[3];
    unsigned inc[3], ld[3];
    const bool useC = (wv < 4);
    {
        int ts[3] = {wv, wv + 8, useC ? wv + 16 : 12};
#pragma unroll
        for (int i = 0; i < 3; ++i) {
            int tt = ts[i];
            if (tt < 8) {
                sp[i] = K96 + (size_t)(b * S_ + tt * 8 + lr) * QROW_ + h * 96 + g * 8;
                inc[i] = 64 * QROW_;  ld[i] = tt * 1024;
            } else if (tt < 12) {
                int rr = (tt - 8) * 16 + (lane >> 2);
                sp[i] = K96 + (size_t)(b * S_ + rr) * QROW_ + h * 96 + 64 + g4 * 8;
                inc[i] = 64 * QROW_;  ld[i] = 8192 + (tt - 8) * 1024;
            } else {
                sp[i] = Vtg + (size_t)(h * 64 + (tt - 12) * 8 + lr) * (size_t)M_
                        + b * S_ + g * 8;
                inc[i] = 64;          ld[i] = 12288 + (tt - 12) * 1024;
            }
            inc[i] = __builtin_amdgcn_readfirstlane(inc[i]);
            ld[i] = __builtin_amdgcn_readfirstlane(ld[i]);
        }
    }

    // ---- Q direct global->VGPR: qf[ds] covers d = ds*32 + quad*8 ..+7
    s16x8 qf[3];
    {
        const unsigned short* qp = Q96 + (size_t)(b * S_ + q0 + wv * 16 + lq) * QROW_
                                   + h * 96 + quad * 8;
#pragma unroll
        for (int ds = 0; ds < 3; ++ds)
            qf[ds] = *(const s16x8*)(qp + ds * 32);
    }

    f32x4 o[4] = {};
    float lpart = 0.f;
    unsigned char* Pb = smem + 40960;

    // ---- prologue: stage tile 0 -> buf0
#pragma unroll
    for (int i = 0; i < 3; ++i)
        if (i < 2 || useC) { GLDS16(sp[i], smem + ld[i]); sp[i] += inc[i]; }

    for (int kt = 0; kt < 32; ++kt) {
        __syncthreads();   // stage(kt) drained; all waves past compute(kt-1)
        unsigned char* cur = smem + (kt & 1) * 20480;

        if (kt + 1 < 32) {
            unsigned char* dst = smem + ((kt + 1) & 1) * 20480;
#pragma unroll
            for (int i = 0; i < 3; ++i)
                if (i < 2 || useC) { GLDS16(sp[i], dst + ld[i]); sp[i] += inc[i]; }
        }

        // ---- scores S^T = K * Q^T  (A=K frag, B=Q frag); q = wv*16+lq
        f32x4 st[4] = {};
#pragma unroll
        for (int ka = 0; ka < 4; ++ka) {
            int key = ka * 16 + lq;
            __builtin_amdgcn_s_setprio(1);
#pragma unroll
            for (int ds = 0; ds < 3; ++ds) {
                s16x8 kf;
                if (ds < 2)
                    kf = *(const s16x8*)(cur + key * 128 + (((ds * 4 + quad) ^ (key & 7)) * 16));
                else
                    kf = *(const s16x8*)(cur + 8192 + key * 64 + ((quad ^ ((key >> 1) & 3)) * 16));
                st[ka] = __builtin_amdgcn_mfma_f32_16x16x32_bf16(
                    kf, qf[ds], st[ka], 0, 0, 0);
            }
            __builtin_amdgcn_s_setprio(0);
        }

        // ---- fixed-max softmax; P[q][k] bf16 via packed cvt
#pragma unroll
        for (int ka = 0; ka < 4; ++ka) {
            float p0 = EXP2(st[ka][0]);
            float p1 = EXP2(st[ka][1]);
            float p2 = EXP2(st[ka][2]);
            float p3 = EXP2(st[ka][3]);
            lpart += (p0 + p1) + (p2 + p3);
            int q = wv * 16 + lq;
            int c = ka * 2 + (quad >> 1);
            unsigned char* pp = Pb + q * 128 + ((c ^ (q & 7)) * 16) + (quad & 1) * 8;
            uint2 w = {pk2(p0, p1), pk2(p2, p3)};
            *(uint2*)pp = w;
        }

        // ---- PV: O += P @ V   (A=P from LDS, B=V^T rows d)
        {
            int q = wv * 16 + lq;
            s16x8 pA[2];
#pragma unroll
            for (int kk = 0; kk < 2; ++kk) {
                int pos = (kk * 4 + quad) ^ (q & 7);
                pA[kk] = *(const s16x8*)(Pb + q * 128 + pos * 16);
            }
            __builtin_amdgcn_s_setprio(1);
#pragma unroll
            for (int ni = 0; ni < 4; ++ni) {
                int d = ni * 16 + lq;
#pragma unroll
                for (int kk = 0; kk < 2; ++kk) {
                    int pos = (kk * 4 + quad) ^ (d & 7);
                    s16x8 vB = *(const s16x8*)(cur + 12288 + d * 128 + pos * 16);
                    o[ni] = __builtin_amdgcn_mfma_f32_16x16x32_bf16(
                        pA[kk], vB, o[ni], 0, 0, 0);
                }
            }
            __builtin_amdgcn_s_setprio(0);
        }
    }

    // ---- epilogue
    {
        float l = lpart;
        l += __shfl_xor(l, 16);
        l += __shfl_xor(l, 32);
        float inv = 1.0f / l;
        float invr[4];
#pragma unroll
        for (int r = 0; r < 4; ++r)
            invr[r] = __shfl(inv, quad * 4 + r);
#pragma unroll
        for (int r = 0; r < 4; ++r) {
            int row = q0 + wv * 16 + quad * 4 + r;
#pragma unroll
            for (int ni = 0; ni < 4; ++ni)
                ctxb[(size_t)(b * S_ + row) * 1024 + h * 64 + ni * 16 + lq] =
                    f2bf(o[ni][r] * invr[r]);
        }
    }
}

// ---------------------------------------------------------------- launch
extern "C" void kernel_launch(void* const* d_in, const int* in_sizes, int n_in,
                              void* d_out, int out_size, void* d_ws, size_t ws_size,
                              hipStream_t stream)
{
    const float* x        = (const float*)d_in[0];
    const float* pitch_pc = (const float*)d_in[1];
    const float* bass_pc  = (const float*)d_in[2];
    const float* Wpq = (const float*)d_in[3];   const float* bpq = (const float*)d_in[4];
    const float* Whq = (const float*)d_in[5];   const float* bhq = (const float*)d_in[6];
    const float* Wvq = (const float*)d_in[7];   const float* bvq = (const float*)d_in[8];
    const float* Wk  = (const float*)d_in[9];   const float* bk  = (const float*)d_in[10];
    const float* Wv  = (const float*)d_in[11];  const float* bv  = (const float*)d_in[12];
    const float* Wo  = (const float*)d_in[13];  const float* bo  = (const float*)d_in[14];
    const float* Wc  = (const float*)d_in[15];  const float* bc  = (const float*)d_in[16];
    const float* Wb  = (const float*)d_in[17];  const float* bb  = (const float*)d_in[18];
    (void)bc; (void)bb;   // key-independent score shifts: softmax-invariant

    char* ws = (char*)d_ws;
    unsigned short* xb    = (unsigned short*)(ws);                     // 8 MB @0
    unsigned short* W3t   = (unsigned short*)(ws + 8388608);           // 6 MB (Bt rows 0..3071)
    unsigned short* Whcvt = (unsigned short*)(ws + 14680064);          // 768 KB (rows 3072..3455)
    unsigned short* Wot   = (unsigned short*)(ws + 15466496);          // 2 MB
    float*          bias5 = (float*)         (ws + 17563648);          // 13.5 KB (3456)
    unsigned short* Q96   = (unsigned short*)(ws + 17577472);          // 12.6 MB
    unsigned short* K96   = (unsigned short*)(ws + 30160384);          // 12.6 MB
    unsigned short* Vtg   = (unsigned short*)(ws + 42743296);          // 8 MB
    unsigned short* ctxb  = (unsigned short*)(ws + 51131904);          // 8 MB

    PrepArgs pa;
    pa.x = x; pa.pitch_pc = pitch_pc; pa.bass_pc = bass_pc;
    pa.Wc = Wc; pa.Wb = Wb;
    pa.Whq = Whq; pa.bhq = bhq; pa.Wvq = Wvq; pa.bvq = bvq;
    pa.wsrc[0] = Wpq; pa.wsrc[1] = Wk; pa.wsrc[2] = Wv; pa.wsrc[3] = Wo;
    pa.wdst[0] = W3t;
    pa.wdst[1] = W3t + (size_t)1024 * 1024;
    pa.wdst[2] = W3t + (size_t)2048 * 1024;
    pa.wdst[3] = Wot;
    pa.bsrc[0] = bpq; pa.bsrc[1] = bk; pa.bsrc[2] = bv;
    pa.bias5 = bias5; pa.Whcvt = Whcvt;
    pa.xb = xb; pa.Q96 = Q96; pa.K96 = K96;

    prep_kernel<<<dim3(4096 + 1024 + 12 + 384 + 256), 256, 0, stream>>>(pa);

    gemm_k<0><<<dim3(27, 32), 256, 0, stream>>>(xb, W3t, bias5, Q96, K96, Vtg, nullptr);

    attn_kernel<<<dim3(B_ * H_, S_ / ATQ_), 512, 57344, stream>>>(Q96, K96, Vtg, ctxb);

    gemm_k<1><<<dim3(8, 32), 256, 0, stream>>>(ctxb, Wot, bo, nullptr, nullptr, nullptr,
                                               (float*)d_out);
}

// Round 8
// 277.460 us; speedup vs baseline: 1.0571x; 1.0213x over previous
//
#include <hip/hip_runtime.h>
#include <hip/hip_bf16.h>
#include <math.h>

// ChordAwareTransformer bf16-MFMA pipeline, round 14.
// R14 = R13 (rank-12 score refactor, attn 65us verified) + gemm0 fixes:
//  * XCD-aware block swizzle (T1): 864/256 blocks both %8==0; bijective
//    (bid&7)*cpx + bid>>3 -> each XCD owns 4 m-rows x all n-tiles; A slice
//    1 MB fits per-XCD L2 (R13: FETCH 75MB vs 15MB ideal, A re-fetched).
//  * wsel0/1 epilogue: LDS-transpose then 128B-contiguous row stores
//    (R13: 64 scalar 2B stores/thread @3KB stride = 2B-granular scatter).
//    C-tile in dead staging LDS, chunk-XOR pos=(col>>3)^(row&7) (~4-way).
// R13 recap: QK inner dim 192->96 via fold Whq@Wc^T (rank-12, exact);
// gemm0 N=3456; attn R8 structure d=96, Q direct->VGPR.
// MFMA layouts (HW-verified): A[m=lane&15][k=quad*8+j], B[k][n=lane&15],
// C/D row=quad*4+reg, col=lane&15.

#define D_    1024
#define H_    16
#define B_    2
#define S_    2048
#define M_    (B_*S_)
#define QROW_ 1536          // Q96/K96 row stride in shorts (16 heads * 96)

#define QSCALE_ (1.44269504f / 24.0f)   // log2e * (1/sqrt(64)) / 3

#if __has_builtin(__builtin_amdgcn_exp2f)
#define EXP2(x) __builtin_amdgcn_exp2f(x)
#else
#define EXP2(x) exp2f(x)
#endif

typedef __attribute__((ext_vector_type(8))) short s16x8;
typedef __attribute__((ext_vector_type(4))) float f32x4;

__device__ __forceinline__ unsigned short f2bf(float f) {
    unsigned u = __builtin_bit_cast(unsigned, f);
    u += 0x7fff + ((u >> 16) & 1);          // RNE
    return (unsigned short)(u >> 16);
}
__device__ __forceinline__ unsigned pk2(float a, float b) {
    __hip_bfloat162 h = __float22bfloat162_rn(float2{a, b});
    unsigned r;
    __builtin_memcpy(&r, &h, 4);
    return r;
}

#define GLDS16(gp, lp) \
    __builtin_amdgcn_global_load_lds((const __attribute__((address_space(1))) void*)(gp), \
                                     (__attribute__((address_space(3))) void*)(lp), 16, 0, 0)

// ---------------------------------------------------------------- prep (fused)
struct PrepArgs {
    const float* x;
    const float* pitch_pc; const float* bass_pc;
    const float* Wc; const float* Wb;
    const float* Whq; const float* bhq;
    const float* Wvq; const float* bvq;
    const float* wsrc[4]; unsigned short* wdst[4];   // Wpq,Wk,Wv,Wo
    const float* bsrc[3]; float* bias5;              // bpq,bk,bv
    unsigned short* Whcvt;                           // 384 x 1024 (Bt rows 3072..3455)
    unsigned short* xb; unsigned short* Q96; unsigned short* K96;
};

__global__ __launch_bounds__(256) void prep_kernel(PrepArgs a) {
    __shared__ unsigned short t[64][72];
    int bx = blockIdx.x;
    const int tid = threadIdx.x;

    if (bx < 4096) {                       // ---- cvt_x (fp32 -> bf16)
        int i = (bx * 256 + tid) * 4;
        float4 v = *(const float4*)(a.x + i);
        uint2 o = {pk2(v.x, v.y), pk2(v.z, v.w)};
        *(uint2*)(a.xb + i) = o;
        return;
    }
    bx -= 4096;
    if (bx < 1024) {                       // ---- wtrans (4 weights, 64x64 tiles)
        int z = bx >> 8, rem = bx & 255;
        const float* src = a.wsrc[z];
        unsigned short* dst = a.wdst[z];
        int k0 = (rem >> 4) * 64, n0 = (rem & 15) * 64;
        int r = tid >> 2, c0 = (tid & 3) * 16;
#pragma unroll
        for (int i = 0; i < 4; ++i) {
            float4 v = *(const float4*)(src + (size_t)(k0 + r) * 1024 + n0 + c0 + i * 4);
            ushort4 o = {f2bf(v.x), f2bf(v.y), f2bf(v.z), f2bf(v.w)};
            *(ushort4*)&t[r][c0 + i * 4] = o;
        }
        __syncthreads();
#pragma unroll
        for (int i = 0; i < 4; ++i) {
            ushort4 o = {t[c0 + i*4 + 0][r], t[c0 + i*4 + 1][r],
                         t[c0 + i*4 + 2][r], t[c0 + i*4 + 3][r]};
            *(ushort4*)(dst + (size_t)(n0 + r) * 1024 + k0 + c0 + i * 4) = o;
        }
        return;
    }
    bx -= 1024;
    if (bx < 12) {                         // ---- bpack (bpq,bk,bv)
        int i = bx * 256 + tid;
        a.bias5[i] = a.bsrc[i >> 10][i & 1023];
        return;
    }
    bx -= 12;
    if (bx < 384) {                        // ---- fold: Whcvt row j (Bt layout)
        int j = bx;
        int h = j / 24, r = j - h * 24;
        const float* src = (r < 12) ? a.Whq : a.Wvq;
        const float* pcw = (r < 12) ? a.Wc  : a.Wb;
        const float* bsr = (r < 12) ? a.bhq : a.bvq;
        int i = (r < 12) ? r : r - 12;
        int hb = h * 64;
#pragma unroll
        for (int ro = 0; ro < 4; ++ro) {
            int row = tid + ro * 256;
            float acc = 0.f;
#pragma unroll
            for (int d = 0; d < 64; ++d)
                acc = fmaf(src[(size_t)row * 1024 + hb + d], pcw[i * 1024 + hb + d], acc);
            a.Whcvt[(size_t)j * 1024 + row] = f2bf(acc);
        }
        if (tid == 0) {
            float bacc = 0.f;
            for (int d = 0; d < 64; ++d)
                bacc = fmaf(bsr[hb + d], pcw[i * 1024 + hb + d], bacc);
            a.bias5[3072 + j] = bacc;
        }
        return;
    }
    bx -= 384;
    {                                      // ---- pcpack: K96 pc cols + pads; Q96 pads
        int idx = bx * 256 + tid;          // 65536 = M*H
        int m = idx >> 4, h = idx & 15;
        int s = m & (S_ - 1);
        unsigned short buf[32];
#pragma unroll
        for (int i = 0; i < 12; ++i) buf[i] = f2bf(a.pitch_pc[s * 12 + i]);
        buf[12] = buf[13] = buf[14] = buf[15] = 0;
#pragma unroll
        for (int i = 0; i < 12; ++i) buf[16 + i] = f2bf(a.bass_pc[s * 12 + i]);
        buf[28] = buf[29] = buf[30] = buf[31] = 0;
        unsigned short* kd = a.K96 + (size_t)m * QROW_ + h * 96 + 64;
#pragma unroll
        for (int i = 0; i < 4; ++i)
            *(uint4*)(kd + i * 8) = *(uint4*)&buf[i * 8];
        unsigned short* qd = a.Q96 + (size_t)m * QROW_ + h * 96 + 64;
        uint2 z = {0u, 0u};
        *(uint2*)(qd + 12) = z;            // cols 76..79
        *(uint2*)(qd + 28) = z;            // cols 92..95
    }
}

// ---------------------------------------------------------------- MFMA GEMM
// C[M x N] = A[M x 1024] @ Bt^T + bias.  BK=32, double-buffered, one barrier
// per K-tile. XCD-swizzled block ids (nwg%8==0 both modes).
// MODE 0 (N=3456): wsel0 pitch_q*QS -> Q96; wsel1 k -> K96 (both via LDS
//   transpose epilogue, 128B row stores); wsel2 v -> Vt^T (uint2, coalesced);
//   wsel3 hq/vq*QS -> Q96 cols 64+/68+ (scalar, 3 tiles only).
// MODE 1: N=1024, fp32 out.
template<int MODE>
__global__ __launch_bounds__(256) void gemm_k(
    const unsigned short* __restrict__ A, const unsigned short* __restrict__ Bt,
    const float* __restrict__ bias, unsigned short* __restrict__ Qb,
    unsigned short* __restrict__ Kb, unsigned short* __restrict__ Vt,
    float* __restrict__ Cf)
{
    __shared__ __align__(16) unsigned char lds[32768];
    const int tid = threadIdx.x;
    const int wv = tid >> 6, lane = tid & 63;
    const int lq = lane & 15, quad = lane >> 4;
    const int wm = wv >> 1, wn = wv & 1;

    // XCD-aware swizzle: each XCD gets a contiguous chunk (nwg % 8 == 0)
    const unsigned bid = blockIdx.y * gridDim.x + blockIdx.x;
    const unsigned cpx = (gridDim.x * gridDim.y) >> 3;
    const unsigned swz = (bid & 7) * cpx + (bid >> 3);
    const int m0 = (int)(swz / gridDim.x) * 128;
    const int n0 = (int)(swz % gridDim.x) * 128;

    const int sr = lane >> 2;
    const int sc = (lane & 3) ^ ((lane >> 3) & 3);
    const unsigned short* Abase = A + (size_t)m0 * 1024 + sc * 8;
    const unsigned short* Bbase = Bt + (size_t)n0 * 1024 + sc * 8;

    f32x4 acc[4][4] = {};

#pragma unroll
    for (int j = 0; j < 2; ++j) {
        int seg = wv * 2 + j;
        GLDS16(Abase + (size_t)(seg * 16 + sr) * 1024, lds + seg * 1024);
        GLDS16(Bbase + (size_t)(seg * 16 + sr) * 1024, lds + 8192 + seg * 1024);
    }

    for (int kt = 0; kt < 32; ++kt) {
        __syncthreads();
        unsigned char* cur = lds + (kt & 1) * 16384;

        if (kt + 1 < 32) {
            const int k0n = (kt + 1) * 32;
            unsigned char* dst = lds + ((kt + 1) & 1) * 16384;
#pragma unroll
            for (int j = 0; j < 2; ++j) {
                int seg = wv * 2 + j;
                GLDS16(Abase + (size_t)(seg * 16 + sr) * 1024 + k0n, dst + seg * 1024);
                GLDS16(Bbase + (size_t)(seg * 16 + sr) * 1024 + k0n, dst + 8192 + seg * 1024);
            }
        }

        s16x8 aF[4], bF[4];
#pragma unroll
        for (int mi = 0; mi < 4; ++mi) {
            int row = wm * 64 + mi * 16 + lq;
            aF[mi] = *(const s16x8*)(cur + row * 64 + ((quad ^ ((row >> 1) & 3)) * 16));
        }
#pragma unroll
        for (int ni = 0; ni < 4; ++ni) {
            int row = wn * 64 + ni * 16 + lq;
            bF[ni] = *(const s16x8*)(cur + 8192 + row * 64 + ((quad ^ ((row >> 1) & 3)) * 16));
        }
#pragma unroll
        for (int mi = 0; mi < 4; ++mi)
#pragma unroll
            for (int ni = 0; ni < 4; ++ni)
                acc[mi][ni] = __builtin_amdgcn_mfma_f32_16x16x32_bf16(
                    aF[mi], bF[ni], acc[mi][ni], 0, 0, 0);
    }

    if (MODE == 0) {
        const int wsel = n0 >> 10;
        if (wsel <= 1) {
            // ---- LDS-transpose epilogue: C tile [128 m][128 n] bf16 in lds,
            // chunk pos = (col>>3) ^ (row&7); then 128B-contiguous row stores.
            const float sc2 = (wsel == 0) ? QSCALE_ : 1.0f;
            unsigned short* lt = (unsigned short*)lds;
            __syncthreads();   // all waves done reading staging bufs
#pragma unroll
            for (int ni = 0; ni < 4; ++ni) {
                int col = wn * 64 + ni * 16 + lq;
                float bv = bias[n0 + col];
#pragma unroll
                for (int mi = 0; mi < 4; ++mi) {
#pragma unroll
                    for (int r = 0; r < 4; ++r) {
                        int row = wm * 64 + mi * 16 + quad * 4 + r;
                        int pos = (col >> 3) ^ (row & 7);
                        lt[row * 128 + pos * 8 + (col & 7)] =
                            f2bf((acc[mi][ni][r] + bv) * sc2);
                    }
                }
            }
            __syncthreads();
            const int row = tid >> 1, seg = tid & 1;
            const int nl0 = n0 & 1023;
            unsigned short* dstp = (wsel == 0) ? Qb : Kb;
            unsigned short* dbase = dstp + (size_t)(m0 + row) * QROW_
                                    + (nl0 >> 6) * 96 + seg * 96;
#pragma unroll
            for (int i = 0; i < 8; ++i) {
                int c = seg * 8 + i;
                int pos = c ^ (row & 7);
                *(uint4*)(dbase + i * 8) = *(const uint4*)(lt + row * 128 + pos * 8);
            }
        } else if (wsel == 2) {            // v -> Vt^T (bf16 pairs, coalesced on m)
#pragma unroll
            for (int ni = 0; ni < 4; ++ni) {
                int n = n0 + wn * 64 + ni * 16 + lq;
                float bv = bias[n];
                int nl = n - 2048, h = nl >> 6, d = nl & 63;
#pragma unroll
                for (int mi = 0; mi < 4; ++mi) {
                    int mrow = m0 + wm * 64 + mi * 16 + quad * 4;
                    uint2 w = {pk2(acc[mi][ni][0] + bv, acc[mi][ni][1] + bv),
                               pk2(acc[mi][ni][2] + bv, acc[mi][ni][3] + bv)};
                    *(uint2*)(Vt + ((size_t)h * 64 + d) * (size_t)M_ + mrow) = w;
                }
            }
        } else {                           // wsel3: hq/vq -> Q96, scaled (3 tiles)
#pragma unroll
            for (int ni = 0; ni < 4; ++ni) {
                int n = n0 + wn * 64 + ni * 16 + lq;
                float bv = bias[n];
                int j = n - 3072;
                int h = j / 24, r = j - h * 24;
                int col = h * 96 + (r < 12 ? 64 + r : 68 + r);
#pragma unroll
                for (int mi = 0; mi < 4; ++mi) {
                    int mrow = m0 + wm * 64 + mi * 16 + quad * 4;
#pragma unroll
                    for (int rr = 0; rr < 4; ++rr)
                        Qb[(size_t)(mrow + rr) * QROW_ + col] =
                            f2bf((acc[mi][ni][rr] + bv) * QSCALE_);
                }
            }
        }
    } else {
#pragma unroll
        for (int ni = 0; ni < 4; ++ni) {
            int n = n0 + wn * 64 + ni * 16 + lq;
            float bv = bias[n];
#pragma unroll
            for (int mi = 0; mi < 4; ++mi) {
                int mrow = m0 + wm * 64 + mi * 16 + quad * 4;
#pragma unroll
                for (int rr = 0; rr < 4; ++rr)
                    Cf[(size_t)(mrow + rr) * 1024 + n] = acc[mi][ni][rr] + bv;
            }
        }
    }
}

// ---------------------------------------------------------------- attention
// R8 structure, d=96 (verified 65us in R13 — unchanged).
// Block: one (b,h), 128 q, 512 thr (8 waves x 16 q). 32 K-tiles of 64 keys.
// LDS 57344: bufs @0/@20480 (20KB: K seg0 [64k][128B] @0 pos c^(key&7);
// K seg1 [64k][64B] @8192 pos c^((key>>1)&3); V [64d][128B] @12288 pos
// c^(d&7)); P @40960 [128q][128B] pos c^(q&7). Q direct global->VGPR.
#define ATQ_ 128

__global__ __launch_bounds__(512, 2) void attn_kernel(
    const unsigned short* __restrict__ Q96, const unsigned short* __restrict__ K96,
    const unsigned short* __restrict__ Vtg, unsigned short* __restrict__ ctxb)
{
    extern __shared__ __align__(16) unsigned char smem[];
    const int tid = threadIdx.x;
    const int wv = tid >> 6, lane = tid & 63;   // wv 0..7
    const int lq = lane & 15, quad = lane >> 4;
    const int bh = blockIdx.x;
    const int b = bh >> 4, h = bh & 15;
    const int q0 = blockIdx.y * ATQ_;
    const int lr = lane >> 3;                   // 128B-row staging: row-in-KB
    const int g = (lane & 7) ^ lr;              // source chunk
    const int g4 = (lane & 3) ^ ((lane >> 3) & 3);  // 64B-row staging chunk

    // ---- staging slots: A=wv (K seg0), B=wv+8, C=wv+16 (wv<4 only)
    const unsigned short* sp[3];
    unsigned inc[3], ld[3];
    const bool useC = (wv < 4);
    {
        int ts[3] = {wv, wv + 8, useC ? wv + 16 : 12};
#pragma unroll
        for (int i = 0; i < 3; ++i) {
            int tt = ts[i];
            if (tt < 8) {
                sp[i] = K96 + (size_t)(b * S_ + tt * 8 + lr) * QROW_ + h * 96 + g * 8;
                inc[i] = 64 * QROW_;  ld[i] = tt * 1024;
            } else if (tt < 12) {
                int rr = (tt - 8) * 16 + (lane >> 2);
                sp[i] = K96 + (size_t)(b * S_ + rr) * QROW_ + h * 96 + 64 + g4 * 8;
                inc[i] = 64 * QROW_;  ld[i] = 8192 + (tt - 8) * 1024;
            } else {
                sp[i] = Vtg + (size_t)(h * 64 + (tt - 12) * 8 + lr) * (size_t)M_
                        + b * S_ + g * 8;
                inc[i] = 64;          ld[i] = 12288 + (tt - 12) * 1024;
            }
            inc[i] = __builtin_amdgcn_readfirstlane(inc[i]);
            ld[i] = __builtin_amdgcn_readfirstlane(ld[i]);
        }
    }

    // ---- Q direct global->VGPR: qf[ds] covers d = ds*32 + quad*8 ..+7
    s16x8 qf[3];
    {
        const unsigned short* qp = Q96 + (size_t)(b * S_ + q0 + wv * 16 + lq) * QROW_
                                   + h * 96 + quad * 8;
#pragma unroll
        for (int ds = 0; ds < 3; ++ds)
            qf[ds] = *(const s16x8*)(qp + ds * 32);
    }

    f32x4 o[4] = {};
    float lpart = 0.f;
    unsigned char* Pb = smem + 40960;

    // ---- prologue: stage tile 0 -> buf0
#pragma unroll
    for (int i = 0; i < 3; ++i)
        if (i < 2 || useC) { GLDS16(sp[i], smem + ld[i]); sp[i] += inc[i]; }

    for (int kt = 0; kt < 32; ++kt) {
        __syncthreads();   // stage(kt) drained; all waves past compute(kt-1)
        unsigned char* cur = smem + (kt & 1) * 20480;

        if (kt + 1 < 32) {
            unsigned char* dst = smem + ((kt + 1) & 1) * 20480;
#pragma unroll
            for (int i = 0; i < 3; ++i)
                if (i < 2 || useC) { GLDS16(sp[i], dst + ld[i]); sp[i] += inc[i]; }
        }

        // ---- scores S^T = K * Q^T  (A=K frag, B=Q frag); q = wv*16+lq
        f32x4 st[4] = {};
#pragma unroll
        for (int ka = 0; ka < 4; ++ka) {
            int key = ka * 16 + lq;
            __builtin_amdgcn_s_setprio(1);
#pragma unroll
            for (int ds = 0; ds < 3; ++ds) {
                s16x8 kf;
                if (ds < 2)
                    kf = *(const s16x8*)(cur + key * 128 + (((ds * 4 + quad) ^ (key & 7)) * 16));
                else
                    kf = *(const s16x8*)(cur + 8192 + key * 64 + ((quad ^ ((key >> 1) & 3)) * 16));
                st[ka] = __builtin_amdgcn_mfma_f32_16x16x32_bf16(
                    kf, qf[ds], st[ka], 0, 0, 0);
            }
            __builtin_amdgcn_s_setprio(0);
        }

        // ---- fixed-max softmax; P[q][k] bf16 via packed cvt
#pragma unroll
        for (int ka = 0; ka < 4; ++ka) {
            float p0 = EXP2(st[ka][0]);
            float p1 = EXP2(st[ka][1]);
            float p2 = EXP2(st[ka][2]);
            float p3 = EXP2(st[ka][3]);
            lpart += (p0 + p1) + (p2 + p3);
            int q = wv * 16 + lq;
            int c = ka * 2 + (quad >> 1);
            unsigned char* pp = Pb + q * 128 + ((c ^ (q & 7)) * 16) + (quad & 1) * 8;
            uint2 w = {pk2(p0, p1), pk2(p2, p3)};
            *(uint2*)pp = w;
        }

        // ---- PV: O += P @ V   (A=P from LDS, B=V^T rows d)
        {
            int q = wv * 16 + lq;
            s16x8 pA[2];
#pragma unroll
            for (int kk = 0; kk < 2; ++kk) {
                int pos = (kk * 4 + quad) ^ (q & 7);
                pA[kk] = *(const s16x8*)(Pb + q * 128 + pos * 16);
            }
            __builtin_amdgcn_s_setprio(1);
#pragma unroll
            for (int ni = 0; ni < 4; ++ni) {
                int d = ni * 16 + lq;
#pragma unroll
                for (int kk = 0; kk < 2; ++kk) {
                    int pos = (kk * 4 + quad) ^ (d & 7);
                    s16x8 vB = *(const s16x8*)(cur + 12288 + d * 128 + pos * 16);
                    o[ni] = __builtin_amdgcn_mfma_f32_16x16x32_bf16(
                        pA[kk], vB, o[ni], 0, 0, 0);
                }
            }
            __builtin_amdgcn_s_setprio(0);
        }
    }

    // ---- epilogue
    {
        float l = lpart;
        l += __shfl_xor(l, 16);
        l += __shfl_xor(l, 32);
        float inv = 1.0f / l;
        float invr[4];
#pragma unroll
        for (int r = 0; r < 4; ++r)
            invr[r] = __shfl(inv, quad * 4 + r);
#pragma unroll
        for (int r = 0; r < 4; ++r) {
            int row = q0 + wv * 16 + quad * 4 + r;
#pragma unroll
            for (int ni = 0; ni < 4; ++ni)
                ctxb[(size_t)(b * S_ + row) * 1024 + h * 64 + ni * 16 + lq] =
                    f2bf(o[ni][r] * invr[r]);
        }
    }
}

// ---------------------------------------------------------------- launch
extern "C" void kernel_launch(void* const* d_in, const int* in_sizes, int n_in,
                              void* d_out, int out_size, void* d_ws, size_t ws_size,
                              hipStream_t stream)
{
    const float* x        = (const float*)d_in[0];
    const float* pitch_pc = (const float*)d_in[1];
    const float* bass_pc  = (const float*)d_in[2];
    const float* Wpq = (const float*)d_in[3];   const float* bpq = (const float*)d_in[4];
    const float* Whq = (const float*)d_in[5];   const float* bhq = (const float*)d_in[6];
    const float* Wvq = (const float*)d_in[7];   const float* bvq = (const float*)d_in[8];
    const float* Wk  = (const float*)d_in[9];   const float* bk  = (const float*)d_in[10];
    const float* Wv  = (const float*)d_in[11];  const float* bv  = (const float*)d_in[12];
    const float* Wo  = (const float*)d_in[13];  const float* bo  = (const float*)d_in[14];
    const float* Wc  = (const float*)d_in[15];  const float* bc  = (const float*)d_in[16];
    const float* Wb  = (const float*)d_in[17];  const float* bb  = (const float*)d_in[18];
    (void)bc; (void)bb;   // key-independent score shifts: softmax-invariant

    char* ws = (char*)d_ws;
    unsigned short* xb    = (unsigned short*)(ws);                     // 8 MB @0
    unsigned short* W3t   = (unsigned short*)(ws + 8388608);           // 6 MB (Bt rows 0..3071)
    unsigned short* Whcvt = (unsigned short*)(ws + 14680064);          // 768 KB (rows 3072..3455)
    unsigned short* Wot   = (unsigned short*)(ws + 15466496);          // 2 MB
    float*          bias5 = (float*)         (ws + 17563648);          // 13.5 KB (3456)
    unsigned short* Q96   = (unsigned short*)(ws + 17577472);          // 12.6 MB
    unsigned short* K96   = (unsigned short*)(ws + 30160384);          // 12.6 MB
    unsigned short* Vtg   = (unsigned short*)(ws + 42743296);          // 8 MB
    unsigned short* ctxb  = (unsigned short*)(ws + 51131904);          // 8 MB

    PrepArgs pa;
    pa.x = x; pa.pitch_pc = pitch_pc; pa.bass_pc = bass_pc;
    pa.Wc = Wc; pa.Wb = Wb;
    pa.Whq = Whq; pa.bhq = bhq; pa.Wvq = Wvq; pa.bvq = bvq;
    pa.wsrc[0] = Wpq; pa.wsrc[1] = Wk; pa.wsrc[2] = Wv; pa.wsrc[3] = Wo;
    pa.wdst[0] = W3t;
    pa.wdst[1] = W3t + (size_t)1024 * 1024;
    pa.wdst[2] = W3t + (size_t)2048 * 1024;
    pa.wdst[3] = Wot;
    pa.bsrc[0] = bpq; pa.bsrc[1] = bk; pa.bsrc[2] = bv;
    pa.bias5 = bias5; pa.Whcvt = Whcvt;
    pa.xb = xb; pa.Q96 = Q96; pa.K96 = K96;

    prep_kernel<<<dim3(4096 + 1024 + 12 + 384 + 256), 256, 0, stream>>>(pa);

    gemm_k<0><<<dim3(27, 32), 256, 0, stream>>>(xb, W3t, bias5, Q96, K96, Vtg, nullptr);

    attn_kernel<<<dim3(B_ * H_, S_ / ATQ_), 512, 57344, stream>>>(Q96, K96, Vtg, ctxb);

    gemm_k<1><<<dim3(8, 32), 256, 0, stream>>>(ctxb, Wot, bo, nullptr, nullptr, nullptr,
                                               (float*)d_out);
}